// Round 1
// baseline (601.171 us; speedup 1.0000x reference)
//
#include <hip/hip_runtime.h>

#define M_NODES 100
#define HDIM 512
#define MH (M_NODES*HDIM)       // 51200
#define WNE_IT (1540*512)

typedef __attribute__((ext_vector_type(8))) short short8v;   // 8 bf16 (4 VGPRs)
typedef __attribute__((ext_vector_type(4))) float float4v;   // MFMA acc

static __device__ __forceinline__ short f2b(float f) {
    union { float f; unsigned u; } v; v.f = f;
    unsigned r = (v.u + 0x7FFF + ((v.u >> 16) & 1)) >> 16;   // RNE
    return (short)r;
}

// ---- front: w3prep (blocks 0..511) + child split-K partials (blocks 512..911)
//      + zero flag/jcount (block 0). Merged to cut dispatch count. ----
__global__ void front_kernel(const float* __restrict__ W_ne, short* __restrict__ W3t,
                             const float* __restrict__ parent, const float* __restrict__ Wp,
                             float* __restrict__ partial_c, int* __restrict__ flagjc) {
    __shared__ float sh[32 * 33];
    int bx = blockIdx.x, t = threadIdx.x;
    if (bx == 0 && t < 101) flagjc[t] = 0;          // flag + jcount[100]
    if (bx < 512) {
        // W3 transpose + bf16: it = bx>>8, kt = bx&15, ht = (bx>>4)&15
        int it = bx >> 8, rem = bx & 255, kt = rem & 15, ht = rem >> 4;
        const float* W3 = W_ne + (size_t)it * WNE_IT + 1024 * 512;
        int tx = t & 31, ty = t >> 5;               // ty 0..7
        #pragma unroll
        for (int r = 0; r < 4; ++r) {
            int k = kt * 32 + ty * 4 + r;
            sh[(ty * 4 + r) * 33 + tx] = W3[(size_t)k * 512 + ht * 32 + tx];
        }
        __syncthreads();
        #pragma unroll
        for (int r = 0; r < 4; ++r) {
            int h = ht * 32 + ty * 4 + r;
            W3t[(size_t)it * 262144 + (size_t)h * 512 + kt * 32 + tx] = f2b(sh[tx * 33 + ty * 4 + r]);
        }
    } else {
        // child partials: b = bx-512; col tile = b%50, k chunk = b/50
        int b = bx - 512;
        int bxx = b % 50, byy = b / 50;
        float* p = sh;                               // 64 floats
        int kc = byy * 64;
        if (t < 64) p[t] = parent[kc + t];
        __syncthreads();
        int o4 = (bxx * 256 + t) * 4;
        float4 acc = make_float4(0.f, 0.f, 0.f, 0.f);
        #pragma unroll 4
        for (int k = 0; k < 64; ++k) {
            float4 w = *(const float4*)(Wp + (size_t)(kc + k) * MH + o4);
            float pv = p[k];
            acc.x += pv * w.x; acc.y += pv * w.y; acc.z += pv * w.z; acc.w += pv * w.w;
        }
        *(float4*)(partial_c + (size_t)byy * MH + o4) = acc;
    }
}

// fold child partials + relu + exists logits (-> out) + node_ok. block = 2 rows.
__global__ void child_red_ex(const float* __restrict__ partial_c, const float* __restrict__ bp,
                             const float* __restrict__ Wex, const float* __restrict__ bex,
                             float* __restrict__ child0, float* __restrict__ exists_out,
                             int* __restrict__ node_ok) {
    __shared__ float red[256];
    int t = threadIdx.x;
    int o4 = (blockIdx.x * 256 + t) * 4;
    float4 s = *(const float4*)(bp + o4);
    #pragma unroll
    for (int q = 0; q < 8; ++q) {
        float4 v = *(const float4*)(partial_c + (size_t)q * MH + o4);
        s.x += v.x; s.y += v.y; s.z += v.z; s.w += v.w;
    }
    s.x = fmaxf(s.x, 0.f); s.y = fmaxf(s.y, 0.f); s.z = fmaxf(s.z, 0.f); s.w = fmaxf(s.w, 0.f);
    *(float4*)(child0 + o4) = s;
    int col = o4 & 511;
    float4 w = *(const float4*)(Wex + col);
    red[t] = s.x * w.x + s.y * w.y + s.z * w.z + s.w * w.w;
    __syncthreads();
    for (int st = 64; st; st >>= 1) {
        if ((t & 127) < st) red[t] += red[t + st];
        __syncthreads();
    }
    if ((t & 127) == 0) {
        int m = blockIdx.x * 2 + (t >> 7);
        float v = red[t] + bex[0];
        exists_out[m] = v;
        node_ok[m] = (v > 0.f) ? 1 : 0;
    }
}

// ---- single-pass quad GEMM: child[100,512] x 4 B's [512,512], bias fused ----
// grid (8, 25), 256 thr. Each thread: 4 output cols (float4), full K=512.
__global__ void gemm_quad(const float* __restrict__ A,
                          const float* __restrict__ B0, const float* __restrict__ B1,
                          const float* __restrict__ B2, const float* __restrict__ B3,
                          const float* __restrict__ bias0, const float* __restrict__ bias2,
                          float* __restrict__ O0, float* __restrict__ O1,
                          float* __restrict__ O2, float* __restrict__ O3) {
    __shared__ float As[4][512];
    int t = threadIdx.x;
    int m0 = blockIdx.y * 4;
    #pragma unroll
    for (int s = 0; s < 2; ++s) {
        int slot = t + s * 256;
        int row = slot >> 7, c4 = (slot & 127) * 4;
        *(float4*)&As[row][c4] = *(const float4*)(A + (size_t)(m0 + row) * 512 + c4);
    }
    __syncthreads();
    int g = blockIdx.x * 64 + (t & 63);        // col4 group 0..511 (uniform 'which' per block)
    int row = t >> 6;
    int which = g >> 7, gg = (g & 127) * 4;
    const float* B = (which == 0) ? B0 : (which == 1) ? B1 : (which == 2) ? B2 : B3;
    const float* bp = B + gg;
    float4 acc = make_float4(0.f, 0.f, 0.f, 0.f);
    #pragma unroll 4
    for (int kk = 0; kk < 512; ++kk) {
        float a = As[row][kk];
        float4 b = *(const float4*)(bp + (size_t)kk * 512);
        acc.x += a * b.x; acc.y += a * b.y; acc.z += a * b.z; acc.w += a * b.w;
    }
    int m = m0 + row;
    if (which == 0) {
        float4 bb = *(const float4*)(bias0 + gg);
        acc.x += bb.x; acc.y += bb.y; acc.z += bb.z; acc.w += bb.w;
        *(float4*)(O0 + (size_t)m * 512 + gg) = acc;
    } else if (which == 1) {
        *(float4*)(O1 + (size_t)m * 512 + gg) = acc;
    } else if (which == 2) {
        float4 bb = *(const float4*)(bias2 + gg);
        acc.x += bb.x; acc.y += bb.y; acc.z += bb.z; acc.w += bb.w;
        *(float4*)(O2 + (size_t)m * 512 + gg) = acc;
    } else {
        *(float4*)(O3 + (size_t)m * 512 + gg) = acc;
    }
}

// ---- single-pass dual-B GEMM (bias+relu fused, no split-K reduce pass) ----
template<int PERM, int K>
__global__ void gemm_dual(const float* __restrict__ A,
                          const float* __restrict__ B1, int N1,
                          const float* __restrict__ bias1, int relu1, float* __restrict__ C1,
                          const float* __restrict__ B2, int N2,
                          const float* __restrict__ bias2, int relu2, float* __restrict__ C2) {
    __shared__ float As[4][K];
    int t = threadIdx.x;
    int m0 = blockIdx.y * 4;
    #pragma unroll
    for (int s = 0; s < K / 256; ++s) {
        int slot = t + s * 256;                   // K float4 slots: 4 rows x K/4
        int row = slot / (K / 4);
        int c4 = (slot - row * (K / 4)) * 4;
        const float* src = PERM
            ? (A + (size_t)(c4 >> 9) * MH + (size_t)(m0 + row) * HDIM + (c4 & 511))
            : (A + (size_t)(m0 + row) * K + c4);
        *(float4*)&As[row][c4] = *(const float4*)src;
    }
    __syncthreads();
    int col = blockIdx.x * 64 + (t & 63);
    int row = t >> 6;
    if (col >= N1 + N2) return;
    bool second = col >= N1;
    const float* B = second ? B2 : B1;
    int nn = second ? col - N1 : col;
    int NN = second ? N2 : N1;
    float acc = 0.f;
    const float* bp = B + nn;
    #pragma unroll 8
    for (int kk = 0; kk < K; ++kk) acc += As[row][kk] * bp[(size_t)kk * NN];
    int m = m0 + row;
    if (!second) {
        acc += bias1 ? bias1[nn] : 0.f;
        if (relu1) acc = fmaxf(acc, 0.f);
        C1[(size_t)m * N1 + nn] = acc;
    } else {
        acc += bias2 ? bias2[nn] : 0.f;
        if (relu2) acc = fmaxf(acc, 0.f);
        C2[(size_t)m * N2 + nn] = acc;
    }
}

// elog (-> out) + active-j compaction; one wave per (i,j) pair
__global__ void elog_kernel(const float* __restrict__ Xi, const float* __restrict__ Xj,
                            const float* __restrict__ Wee, const float* __restrict__ bee,
                            const int* __restrict__ node_ok,
                            float* __restrict__ elog, int* __restrict__ any_flag,
                            int* __restrict__ jcount, int* __restrict__ jlist) {
    int wid = threadIdx.x >> 6, lane = threadIdx.x & 63;
    int pair = blockIdx.x * 4 + wid;
    int i = pair / M_NODES, j = pair - (pair / M_NODES) * M_NODES;
    int k0 = lane * 8;
    float4 xa = *(const float4*)(Xi + (size_t)i * HDIM + k0);
    float4 xb = *(const float4*)(Xi + (size_t)i * HDIM + k0 + 4);
    float4 ya = *(const float4*)(Xj + (size_t)j * HDIM + k0);
    float4 yb = *(const float4*)(Xj + (size_t)j * HDIM + k0 + 4);
    float e0 = fmaxf(xa.x + ya.x, 0.f), e1 = fmaxf(xa.y + ya.y, 0.f);
    float e2 = fmaxf(xa.z + ya.z, 0.f), e3 = fmaxf(xa.w + ya.w, 0.f);
    float e4 = fmaxf(xb.x + yb.x, 0.f), e5 = fmaxf(xb.y + yb.y, 0.f);
    float e6 = fmaxf(xb.z + yb.z, 0.f), e7 = fmaxf(xb.w + yb.w, 0.f);
    float s[4];
    #pragma unroll
    for (int t = 0; t < 4; ++t) {
        float4 wa = *(const float4*)(Wee + t * HDIM + k0);
        float4 wb = *(const float4*)(Wee + t * HDIM + k0 + 4);
        s[t] = e0*wa.x + e1*wa.y + e2*wa.z + e3*wa.w + e4*wb.x + e5*wb.y + e6*wb.z + e7*wb.w;
    }
    #pragma unroll
    for (int off = 32; off; off >>= 1) {
        s[0] += __shfl_down(s[0], off); s[1] += __shfl_down(s[1], off);
        s[2] += __shfl_down(s[2], off); s[3] += __shfl_down(s[3], off);
    }
    if (lane == 0) {
        bool ok = node_ok[i] && node_ok[j];
        float lg0 = s[0] + bee[0], lg1 = s[1] + bee[1], lg2 = s[2] + bee[2], lg3 = s[3] + bee[3];
        elog[pair * 4 + 0] = lg0; elog[pair * 4 + 1] = lg1;
        elog[pair * 4 + 2] = lg2; elog[pair * 4 + 3] = lg3;
        bool any = ok && (lg0 > 0.f || lg1 > 0.f || lg2 > 0.f || lg3 > 0.f);
        if (any) {
            int slot = atomicAdd(&jcount[i], 1);
            jlist[i * 112 + slot] = j;
            if (*(volatile int*)any_flag == 0) atomicOr(any_flag, 1);
        }
    }
}

// ---- fused MFMA message step + reduction: block i loops its j-tiles,
//      accumulates in registers, writes child_next directly. ----
__global__ __launch_bounds__(512) void
msg_fused(const float* __restrict__ Xi, const float* __restrict__ Xj,
          const float* __restrict__ Abuf, const float* __restrict__ Bbuf,
          const short* __restrict__ W3t, const float* __restrict__ W4,
          const float* __restrict__ elog, const int* __restrict__ jcount,
          const int* __restrict__ jlist, const int* __restrict__ any_flag,
          const float* __restrict__ child_prev, float* __restrict__ child_next) {
    __shared__ short ELb[16][520];             // bf16, +8 pad
    __shared__ int jrow[16];
    int i = blockIdx.x;
    int t = threadIdx.x;
    int jcnt = jcount[i];
    if (jcnt == 0) {                           // no edges from i: new = 0 (if any edge globally)
        float v = (*any_flag) ? 0.f : child_prev[(size_t)i * HDIM + t];
        child_next[(size_t)i * HDIM + t] = v;
        return;
    }
    int wave = t >> 6, lane = t & 63;
    int n = lane & 15, quad = lane >> 4;
    int h0w = wave * 64;
    int k0 = (t & 127) * 4;                    // build-phase k offset (same for all 4 slots)
    int r0 = t >> 7;
    float4 xi = *(const float4*)(Xi + (size_t)i * HDIM + k0);   // hoisted: invariant over tiles

    // hoist epilogue constants (per hcol)
    float avalv[4], w40v[4], w41v[4], w42v[4], w43v[4];
    #pragma unroll
    for (int nt = 0; nt < 4; ++nt) {
        int hcol = h0w + nt * 16 + n;
        avalv[nt] = Abuf[(size_t)i * HDIM + hcol];
        w40v[nt] = W4[hcol]; w41v[nt] = W4[HDIM + hcol];
        w42v[nt] = W4[2 * HDIM + hcol]; w43v[nt] = W4[3 * HDIM + hcol];
    }

    float stot[4] = {0.f, 0.f, 0.f, 0.f};
    int ntiles = (jcnt + 15) >> 4;
    for (int jt = 0; jt < ntiles; ++jt) {
        if (t < 16) jrow[t] = (jt * 16 + t < jcnt) ? jlist[i * 112 + jt * 16 + t] : -1;
        __syncthreads();
        #pragma unroll
        for (int s = 0; s < 4; ++s) {
            int row = r0 + s * 4;
            int j = jrow[row];
            short4 b;
            if (j >= 0) {
                float4 xj = *(const float4*)(Xj + (size_t)j * HDIM + k0);
                b.x = f2b(fmaxf(xi.x + xj.x, 0.f));
                b.y = f2b(fmaxf(xi.y + xj.y, 0.f));
                b.z = f2b(fmaxf(xi.z + xj.z, 0.f));
                b.w = f2b(fmaxf(xi.w + xj.w, 0.f));
            } else {
                b.x = b.y = b.z = b.w = 0;
            }
            *(short4*)&ELb[row][k0] = b;
        }
        __syncthreads();

        float4v acc[4];
        #pragma unroll
        for (int nt = 0; nt < 4; ++nt) acc[nt] = (float4v){0.f, 0.f, 0.f, 0.f};
        for (int kc = 0; kc < 16; ++kc) {
            int koff = kc * 32 + quad * 8;
            short8v a = *(const short8v*)&ELb[n][koff];
            #pragma unroll
            for (int nt = 0; nt < 4; ++nt) {
                int hcol = h0w + nt * 16 + n;
                short8v b = *(const short8v*)(W3t + (size_t)hcol * 512 + koff);
                acc[nt] = __builtin_amdgcn_mfma_f32_16x16x32_bf16(a, b, acc[nt], 0, 0, 0);
            }
        }

        // epilogue: lane-local partial over this tile's 4 quad-rows
        #pragma unroll
        for (int nt = 0; nt < 4; ++nt) {
            int hcol = h0w + nt * 16 + n;
            float s = 0.f;
            #pragma unroll
            for (int reg = 0; reg < 4; ++reg) {
                int jj = jrow[quad * 4 + reg];
                if (jj >= 0) {
                    float s0 = avalv[nt] + Bbuf[(size_t)jj * HDIM + hcol] + acc[nt][reg];
                    const float* lgp = elog + ((size_t)i * M_NODES + jj) * 4;
                    float lg;
                    lg = lgp[0]; if (lg > 0.f) s += fmaxf(s0 + lg * w40v[nt], 0.f);
                    lg = lgp[1]; if (lg > 0.f) s += fmaxf(s0 + lg * w41v[nt], 0.f);
                    lg = lgp[2]; if (lg > 0.f) s += fmaxf(s0 + lg * w42v[nt], 0.f);
                    lg = lgp[3]; if (lg > 0.f) s += fmaxf(s0 + lg * w43v[nt], 0.f);
                }
            }
            stot[nt] += s;
        }
        __syncthreads();                       // protect ELb/jrow for next tile
    }

    // cross-quad reduce once, write (jcnt>0 implies any_flag set)
    #pragma unroll
    for (int nt = 0; nt < 4; ++nt) {
        float v = stot[nt];
        v += __shfl_xor(v, 16);
        v += __shfl_xor(v, 32);
        if (lane < 16) child_next[(size_t)i * HDIM + h0w + nt * 16 + n] = v;
    }
}

extern "C" void kernel_launch(void* const* d_in, const int* in_sizes, int n_in,
                              void* d_out, int out_size, void* d_ws, size_t ws_size,
                              hipStream_t stream) {
    const float* parent   = (const float*)d_in[0];
    const float* W_parent = (const float*)d_in[1];
    const float* b_parent = (const float*)d_in[2];
    const float* W_exists = (const float*)d_in[3];
    const float* b_exists = (const float*)d_in[4];
    const float* W_el     = (const float*)d_in[5];
    const float* b_el     = (const float*)d_in[6];
    const float* W_ee     = (const float*)d_in[7];
    const float* b_ee     = (const float*)d_in[8];
    const float* W_ne     = (const float*)d_in[9];
    const float* b_ne     = (const float*)d_in[10];
    const float* W_child  = (const float*)d_in[11];
    const float* b_child  = (const float*)d_in[12];
    const float* W_sem    = (const float*)d_in[13];
    const float* b_sem    = (const float*)d_in[14];
    const float* W_child2 = (const float*)d_in[15];
    const float* b_child2 = (const float*)d_in[16];
    float* out = (float*)d_out;

    float* ws = (float*)d_ws;
    float* child_bufs = ws;                       // 3 * MH
    float* Xi       = ws + 3 * MH;                // MH each
    float* Xj       = Xi + MH;
    float* Abuf     = Xj + MH;
    float* Bbuf     = Abuf + MH;
    int*   node_ok  = (int*)(Bbuf + MH);          // 100
    int*   flag     = node_ok + M_NODES;          // 1
    int*   jcount   = flag + 1;                   // 100 (contiguous with flag)
    int*   jlist    = jcount + 100;               // 100*112 = 11200
    float* partial_c = (float*)(jlist + 11200 + 3);  // 8*MH f32, 16B-aligned (offset 369804)
    short* W3t      = (short*)(partial_c + 8 * MH);  // 2*512*512 bf16 = 1 MB
    float* hbuf     = Xi;                          // alias (dead after msg it1)

    // outputs written in place:
    float* out_child  = out;                      // 51200
    float* out_sem    = out + 51200;              // 5700
    float* out_exists = out + 56900;              // 100
    float* out_elog   = out + 57000;              // 40000

    // 1. w3prep + child split-K partials + zero flag/jcount
    front_kernel<<<912, 256, 0, stream>>>(W_ne, W3t, parent, W_parent, partial_c, flag);

    // 2. child reduce + relu + exists -> out + node_ok
    child_red_ex<<<50, 256, 0, stream>>>(partial_c, b_parent, W_exists, b_exists,
                                         child_bufs, out_exists, node_ok);

    // 3. Xi/Xj/Abuf/Bbuf in one pass (biases fused: Xi+=b_el, Abuf+=b_ne[0])
    gemm_quad<<<dim3(8, 25), 256, 0, stream>>>(child_bufs,
        W_el, W_el + 512 * 512, W_ne, W_ne + 512 * 512,
        b_el, b_ne, Xi, Xj, Abuf, Bbuf);

    // 4. edge logits -> out, compaction
    elog_kernel<<<2500, 256, 0, stream>>>(Xi, Xj, W_ee, b_ee, node_ok, out_elog, flag,
                                          jcount, jlist);

    // 5-7. message iterations (fused reduce)
    for (int it = 0; it < 2; ++it) {
        const float* cprev = child_bufs + it * MH;
        float* cnext = child_bufs + (it + 1) * MH;
        if (it == 1) {
            gemm_dual<0, 512><<<dim3(16, 25), 256, 0, stream>>>(cprev,
                W_ne + WNE_IT, 512, b_ne + 512, 0, Abuf,
                W_ne + WNE_IT + 512 * 512, 512, nullptr, 0, Bbuf);
        }
        msg_fused<<<M_NODES, 512, 0, stream>>>(
            Xi, Xj, Abuf, Bbuf,
            W3t + (size_t)it * 262144,
            W_ne + (size_t)it * WNE_IT + 1536 * 512,
            out_elog, jcount, jlist, flag, cprev, cnext);
    }

    // 8. h = relu(hcat @ W_child + b_child)   (PERM reads [3][100][512] as [100][1536])
    gemm_dual<1, 1536><<<dim3(8, 25), 256, 0, stream>>>(child_bufs,
        W_child, 512, b_child, 1, hbuf,
        nullptr, 0, nullptr, 0, nullptr);

    // 9. child_out + sem -> out directly
    gemm_dual<0, 512><<<dim3(9, 25), 256, 0, stream>>>(hbuf,
        W_child2, 512, b_child2, 1, out_child,
        W_sem, 57, b_sem, 0, out_sem);
}

// Round 2
// 381.950 us; speedup vs baseline: 1.5739x; 1.5739x over previous
//
#include <hip/hip_runtime.h>

#define M_NODES 100
#define HDIM 512
#define MH (M_NODES*HDIM)       // 51200
#define WNE_IT (1540*512)

typedef __attribute__((ext_vector_type(8))) short short8v;   // 8 bf16 (4 VGPRs)
typedef __attribute__((ext_vector_type(4))) float float4v;   // MFMA acc

static __device__ __forceinline__ short f2b(float f) {
    union { float f; unsigned u; } v; v.f = f;
    unsigned r = (v.u + 0x7FFF + ((v.u >> 16) & 1)) >> 16;   // RNE
    return (short)r;
}

// ---- front: w3prep (blocks 0..511) + child split-K partials (blocks 512..911)
//      + zero flag/jcount (block 0). ----
__global__ void front_kernel(const float* __restrict__ W_ne, short* __restrict__ W3t,
                             const float* __restrict__ parent, const float* __restrict__ Wp,
                             float* __restrict__ partial_c, int* __restrict__ flagjc) {
    __shared__ float sh[32 * 33];
    int bx = blockIdx.x, t = threadIdx.x;
    if (bx == 0 && t < 101) flagjc[t] = 0;          // flag + jcount[100]
    if (bx < 512) {
        int it = bx >> 8, rem = bx & 255, kt = rem & 15, ht = rem >> 4;
        const float* W3 = W_ne + (size_t)it * WNE_IT + 1024 * 512;
        int tx = t & 31, ty = t >> 5;               // ty 0..7
        #pragma unroll
        for (int r = 0; r < 4; ++r) {
            int k = kt * 32 + ty * 4 + r;
            sh[(ty * 4 + r) * 33 + tx] = W3[(size_t)k * 512 + ht * 32 + tx];
        }
        __syncthreads();
        #pragma unroll
        for (int r = 0; r < 4; ++r) {
            int h = ht * 32 + ty * 4 + r;
            W3t[(size_t)it * 262144 + (size_t)h * 512 + kt * 32 + tx] = f2b(sh[tx * 33 + ty * 4 + r]);
        }
    } else {
        int b = bx - 512;
        int bxx = b % 50, byy = b / 50;
        float* p = sh;                               // 64 floats
        int kc = byy * 64;
        if (t < 64) p[t] = parent[kc + t];
        __syncthreads();
        int o4 = (bxx * 256 + t) * 4;
        float4 acc = make_float4(0.f, 0.f, 0.f, 0.f);
        #pragma unroll 4
        for (int k = 0; k < 64; ++k) {
            float4 w = *(const float4*)(Wp + (size_t)(kc + k) * MH + o4);
            float pv = p[k];
            acc.x += pv * w.x; acc.y += pv * w.y; acc.z += pv * w.z; acc.w += pv * w.w;
        }
        *(float4*)(partial_c + (size_t)byy * MH + o4) = acc;
    }
}

// fold child partials + relu + exists logits (-> out) + node_ok. block = 2 rows.
__global__ void child_red_ex(const float* __restrict__ partial_c, const float* __restrict__ bp,
                             const float* __restrict__ Wex, const float* __restrict__ bex,
                             float* __restrict__ child0, float* __restrict__ exists_out,
                             int* __restrict__ node_ok) {
    __shared__ float red[256];
    int t = threadIdx.x;
    int o4 = (blockIdx.x * 256 + t) * 4;
    float4 s = *(const float4*)(bp + o4);
    #pragma unroll
    for (int q = 0; q < 8; ++q) {
        float4 v = *(const float4*)(partial_c + (size_t)q * MH + o4);
        s.x += v.x; s.y += v.y; s.z += v.z; s.w += v.w;
    }
    s.x = fmaxf(s.x, 0.f); s.y = fmaxf(s.y, 0.f); s.z = fmaxf(s.z, 0.f); s.w = fmaxf(s.w, 0.f);
    *(float4*)(child0 + o4) = s;
    int col = o4 & 511;
    float4 w = *(const float4*)(Wex + col);
    red[t] = s.x * w.x + s.y * w.y + s.z * w.z + s.w * w.w;
    __syncthreads();
    for (int st = 64; st; st >>= 1) {
        if ((t & 127) < st) red[t] += red[t + st];
        __syncthreads();
    }
    if ((t & 127) == 0) {
        int m = blockIdx.x * 2 + (t >> 7);
        float v = red[t] + bex[0];
        exists_out[m] = v;
        node_ok[m] = (v > 0.f) ? 1 : 0;
    }
}

// ---- split-K GEMM, float4 B-loads, up to 4 B-matrices of 512 cols each ----
// block 256: 64 col4-groups x 4 rows; K-chunk 128. grid (NB*2, 25, K/128).
template<int PERM, int K, int NB>
__global__ void spk_g4(const float* __restrict__ A,
                       const float* __restrict__ B0, const float* __restrict__ B1,
                       const float* __restrict__ B2, const float* __restrict__ B3,
                       float* __restrict__ partial) {
    __shared__ float As[4][128];
    int t = threadIdx.x;
    int m0 = blockIdx.y * 4;
    int kc = blockIdx.z * 128;
    if (t < 128) {
        int row = t >> 5, c4 = (t & 31) * 4;
        int kg = kc + c4;
        const float* src = PERM
            ? (A + (size_t)(kg >> 9) * MH + (size_t)(m0 + row) * HDIM + (kg & 511))
            : (A + (size_t)(m0 + row) * K + kg);
        *(float4*)&As[row][c4] = *(const float4*)src;
    }
    __syncthreads();
    int g = blockIdx.x * 64 + (t & 63);          // col4 group, 'which' uniform per 64-lane wavehalf
    int row = t >> 6, m = m0 + row;
    int which = g >> 7, gg = (g & 127) * 4;
    const float* B = (which == 0) ? B0 : (which == 1) ? B1 : (which == 2) ? B2 : B3;
    const float* bp = B + (size_t)kc * 512 + gg;
    float4 acc = make_float4(0.f, 0.f, 0.f, 0.f);
    #pragma unroll 8
    for (int kk = 0; kk < 128; ++kk) {
        float a = As[row][kk];
        float4 b = *(const float4*)(bp + (size_t)kk * 512);
        acc.x += a * b.x; acc.y += a * b.y; acc.z += a * b.z; acc.w += a * b.w;
    }
    *(float4*)(partial + ((size_t)blockIdx.z * M_NODES + m) * (NB * 512) + (size_t)g * 4) = acc;
}

// fold split-K partials + per-B bias/relu, scatter to up to 4 outputs
__global__ void spk_reduceN(const float* __restrict__ partial, int k_chunks, int NB,
                            float* __restrict__ O0, float* __restrict__ O1,
                            float* __restrict__ O2, float* __restrict__ O3,
                            const float* __restrict__ b0, const float* __restrict__ b1,
                            const float* __restrict__ b2, const float* __restrict__ b3,
                            int relumask) {
    int id = blockIdx.x * 256 + threadIdx.x;     // grid sized exactly: 100*NB*512/256
    int NT = NB << 9;
    int m = id / NT, col = id - m * NT;
    float s = 0.f;
    for (int kc = 0; kc < k_chunks; ++kc)
        s += partial[((size_t)kc * M_NODES + m) * NT + col];
    int which = col >> 9, nn = col & 511;
    const float* bb = (which == 0) ? b0 : (which == 1) ? b1 : (which == 2) ? b2 : b3;
    float* O = (which == 0) ? O0 : (which == 1) ? O1 : (which == 2) ? O2 : O3;
    if (bb) s += bb[nn];
    if ((relumask >> which) & 1) s = fmaxf(s, 0.f);
    O[(size_t)m * 512 + nn] = s;
}

// ---- scalar split-K dual-B GEMM (for ragged N2=57), K-chunk 128 ----
template<int PERM>
__global__ void spk_gemm(const float* __restrict__ A, int K,
                         const float* __restrict__ B1, int N1,
                         const float* __restrict__ B2, int N2,
                         float* __restrict__ partial) {
    __shared__ float As[4][128];
    int t = threadIdx.x;
    int NT = N1 + N2;
    int m0 = blockIdx.y * 4;
    int kc = blockIdx.z * 128;
    if (t < 128) {
        int row = t >> 5, c4 = (t & 31) * 4;
        int kg = kc + c4;
        const float* src = PERM
            ? (A + (size_t)(kg >> 9) * MH + (size_t)(m0 + row) * HDIM + (kg & 511))
            : (A + (size_t)(m0 + row) * K + kg);
        *(float4*)&As[row][c4] = *(const float4*)src;
    }
    __syncthreads();
    int col = blockIdx.x * 64 + (t & 63);
    int row = t >> 6, m = m0 + row;
    if (col >= NT) return;
    bool second = col >= N1;
    const float* B = second ? B2 : B1;
    int nn = second ? col - N1 : col;
    int NN = second ? N2 : N1;
    float acc = 0.f;
    const float* bp = B + (size_t)kc * NN + nn;
    #pragma unroll 8
    for (int kk = 0; kk < 128; ++kk) acc += As[row][kk] * bp[(size_t)kk * NN];
    partial[((size_t)blockIdx.z * M_NODES + m) * NT + col] = acc;
}

__global__ void spk_reduce(const float* __restrict__ partial, int k_chunks,
                           const float* __restrict__ bias1, int relu1,
                           float* __restrict__ C1, int N1,
                           const float* __restrict__ bias2, int relu2,
                           float* __restrict__ C2, int N2) {
    int NT = N1 + N2;
    int id = blockIdx.x * 256 + threadIdx.x;
    if (id >= M_NODES * NT) return;
    int m = id / NT, col = id - m * NT;
    float s = 0.f;
    for (int kc = 0; kc < k_chunks; ++kc)
        s += partial[((size_t)kc * M_NODES + m) * NT + col];
    if (col < N1) {
        s += bias1 ? bias1[col] : 0.f;
        if (relu1) s = fmaxf(s, 0.f);
        C1[(size_t)m * N1 + col] = s;
    } else {
        int nn = col - N1;
        s += bias2 ? bias2[nn] : 0.f;
        if (relu2) s = fmaxf(s, 0.f);
        C2[(size_t)m * N2 + nn] = s;
    }
}

// elog (-> out) + active-j compaction; one wave per (i,j) pair
__global__ void elog_kernel(const float* __restrict__ Xi, const float* __restrict__ Xj,
                            const float* __restrict__ Wee, const float* __restrict__ bee,
                            const int* __restrict__ node_ok,
                            float* __restrict__ elog, int* __restrict__ any_flag,
                            int* __restrict__ jcount, int* __restrict__ jlist) {
    int wid = threadIdx.x >> 6, lane = threadIdx.x & 63;
    int pair = blockIdx.x * 4 + wid;
    int i = pair / M_NODES, j = pair - (pair / M_NODES) * M_NODES;
    int k0 = lane * 8;
    float4 xa = *(const float4*)(Xi + (size_t)i * HDIM + k0);
    float4 xb = *(const float4*)(Xi + (size_t)i * HDIM + k0 + 4);
    float4 ya = *(const float4*)(Xj + (size_t)j * HDIM + k0);
    float4 yb = *(const float4*)(Xj + (size_t)j * HDIM + k0 + 4);
    float e0 = fmaxf(xa.x + ya.x, 0.f), e1 = fmaxf(xa.y + ya.y, 0.f);
    float e2 = fmaxf(xa.z + ya.z, 0.f), e3 = fmaxf(xa.w + ya.w, 0.f);
    float e4 = fmaxf(xb.x + yb.x, 0.f), e5 = fmaxf(xb.y + yb.y, 0.f);
    float e6 = fmaxf(xb.z + yb.z, 0.f), e7 = fmaxf(xb.w + yb.w, 0.f);
    float s[4];
    #pragma unroll
    for (int t = 0; t < 4; ++t) {
        float4 wa = *(const float4*)(Wee + t * HDIM + k0);
        float4 wb = *(const float4*)(Wee + t * HDIM + k0 + 4);
        s[t] = e0*wa.x + e1*wa.y + e2*wa.z + e3*wa.w + e4*wb.x + e5*wb.y + e6*wb.z + e7*wb.w;
    }
    #pragma unroll
    for (int off = 32; off; off >>= 1) {
        s[0] += __shfl_down(s[0], off); s[1] += __shfl_down(s[1], off);
        s[2] += __shfl_down(s[2], off); s[3] += __shfl_down(s[3], off);
    }
    if (lane == 0) {
        bool ok = node_ok[i] && node_ok[j];
        float lg0 = s[0] + bee[0], lg1 = s[1] + bee[1], lg2 = s[2] + bee[2], lg3 = s[3] + bee[3];
        elog[pair * 4 + 0] = lg0; elog[pair * 4 + 1] = lg1;
        elog[pair * 4 + 2] = lg2; elog[pair * 4 + 3] = lg3;
        bool any = ok && (lg0 > 0.f || lg1 > 0.f || lg2 > 0.f || lg3 > 0.f);
        if (any) {
            int slot = atomicAdd(&jcount[i], 1);
            jlist[i * 112 + slot] = j;
            if (*(volatile int*)any_flag == 0) atomicOr(any_flag, 1);
        }
    }
}

// ---- MFMA message step, one block per (jt, i): parallelism restored ----
__global__ __launch_bounds__(512) void
msgmfma(const float* __restrict__ Xi, const float* __restrict__ Xj,
        const float* __restrict__ Abuf, const float* __restrict__ Bbuf,
        const short* __restrict__ W3t, const float* __restrict__ W4,
        const float* __restrict__ elog, const int* __restrict__ jcount,
        const int* __restrict__ jlist, float* __restrict__ partial) {
    __shared__ short ELb[16][520];             // bf16, +8 pad
    __shared__ int jrow[16];
    int i = blockIdx.y;
    int jt = blockIdx.x;
    int jcnt = jcount[i];
    int j0 = jt * 16;
    if (j0 >= jcnt) return;                    // sparse early-exit
    int t = threadIdx.x;
    int wave = t >> 6, lane = t & 63;

    if (t < 16) jrow[t] = (j0 + t < jcnt) ? jlist[i * 112 + j0 + t] : -1;
    __syncthreads();
    int k0 = (t & 127) * 4;
    int r0 = t >> 7;
    float4 xi = *(const float4*)(Xi + (size_t)i * HDIM + k0);
    #pragma unroll
    for (int s = 0; s < 4; ++s) {
        int row = r0 + s * 4;
        int j = jrow[row];
        short4 b;
        if (j >= 0) {
            float4 xj = *(const float4*)(Xj + (size_t)j * HDIM + k0);
            b.x = f2b(fmaxf(xi.x + xj.x, 0.f));
            b.y = f2b(fmaxf(xi.y + xj.y, 0.f));
            b.z = f2b(fmaxf(xi.z + xj.z, 0.f));
            b.w = f2b(fmaxf(xi.w + xj.w, 0.f));
        } else {
            b.x = b.y = b.z = b.w = 0;
        }
        *(short4*)&ELb[row][k0] = b;
    }
    __syncthreads();

    int n = lane & 15, quad = lane >> 4;
    int h0w = wave * 64;
    float4v acc[4];
    #pragma unroll
    for (int nt = 0; nt < 4; ++nt) acc[nt] = (float4v){0.f, 0.f, 0.f, 0.f};

    for (int kc = 0; kc < 16; ++kc) {
        int koff = kc * 32 + quad * 8;
        short8v a = *(const short8v*)&ELb[n][koff];
        #pragma unroll
        for (int nt = 0; nt < 4; ++nt) {
            int hcol = h0w + nt * 16 + n;
            short8v b = *(const short8v*)(W3t + (size_t)hcol * 512 + koff);
            acc[nt] = __builtin_amdgcn_mfma_f32_16x16x32_bf16(a, b, acc[nt], 0, 0, 0);
        }
    }

    // epilogue: C/D col=lane&15 -> hcol, row=quad*4+reg -> tile j-row
    #pragma unroll
    for (int nt = 0; nt < 4; ++nt) {
        int hcol = h0w + nt * 16 + n;
        float aval = Abuf[(size_t)i * HDIM + hcol];
        float w40 = W4[hcol], w41 = W4[HDIM + hcol], w42 = W4[2*HDIM + hcol], w43 = W4[3*HDIM + hcol];
        float s = 0.f;
        #pragma unroll
        for (int reg = 0; reg < 4; ++reg) {
            int jj = jrow[quad * 4 + reg];
            if (jj >= 0) {
                float s0 = aval + Bbuf[(size_t)jj * HDIM + hcol] + acc[nt][reg];
                const float* lgp = elog + ((size_t)i * M_NODES + jj) * 4;
                float lg;
                lg = lgp[0]; if (lg > 0.f) s += fmaxf(s0 + lg * w40, 0.f);
                lg = lgp[1]; if (lg > 0.f) s += fmaxf(s0 + lg * w41, 0.f);
                lg = lgp[2]; if (lg > 0.f) s += fmaxf(s0 + lg * w42, 0.f);
                lg = lgp[3]; if (lg > 0.f) s += fmaxf(s0 + lg * w43, 0.f);
            }
        }
        s += __shfl_xor(s, 16);
        s += __shfl_xor(s, 32);
        if (lane < 16) partial[(size_t)jt * MH + (size_t)i * HDIM + hcol] = s;
    }
}

// fold live jt-partials + any_edge select
__global__ void msgreduce_kernel(const float* __restrict__ partial,
                                 const float* __restrict__ child_prev,
                                 float* __restrict__ child_next,
                                 const int* __restrict__ any_flag,
                                 const int* __restrict__ jcount) {
    int id = blockIdx.x * 256 + threadIdx.x;   // grid 200
    int i = id >> 9;
    int ntiles = (jcount[i] + 15) >> 4;
    float s = 0.f;
    for (int jc = 0; jc < ntiles; ++jc) s += partial[(size_t)jc * MH + id];
    child_next[id] = (*any_flag) ? s : child_prev[id];
}

extern "C" void kernel_launch(void* const* d_in, const int* in_sizes, int n_in,
                              void* d_out, int out_size, void* d_ws, size_t ws_size,
                              hipStream_t stream) {
    const float* parent   = (const float*)d_in[0];
    const float* W_parent = (const float*)d_in[1];
    const float* b_parent = (const float*)d_in[2];
    const float* W_exists = (const float*)d_in[3];
    const float* b_exists = (const float*)d_in[4];
    const float* W_el     = (const float*)d_in[5];
    const float* b_el     = (const float*)d_in[6];
    const float* W_ee     = (const float*)d_in[7];
    const float* b_ee     = (const float*)d_in[8];
    const float* W_ne     = (const float*)d_in[9];
    const float* b_ne     = (const float*)d_in[10];
    const float* W_child  = (const float*)d_in[11];
    const float* b_child  = (const float*)d_in[12];
    const float* W_sem    = (const float*)d_in[13];
    const float* b_sem    = (const float*)d_in[14];
    const float* W_child2 = (const float*)d_in[15];
    const float* b_child2 = (const float*)d_in[16];
    float* out = (float*)d_out;

    float* ws = (float*)d_ws;
    float* child_bufs = ws;                       // 3 * MH
    float* Xi       = ws + 3 * MH;                // MH each
    float* Xj       = Xi + MH;
    float* Abuf     = Xj + MH;
    float* Bbuf     = Abuf + MH;
    int*   node_ok  = (int*)(Bbuf + MH);          // 100
    int*   flag     = node_ok + M_NODES;          // 1
    int*   jcount   = flag + 1;                   // 100 (contiguous with flag)
    int*   jlist    = jcount + 100;               // 100*112 = 11200
    float* scratch  = (float*)(jlist + 11200 + 3);   // 819200 f32 (3.28 MB), 16B-aligned
    short* W3t      = (short*)(scratch + 819200);    // 2*512*512 bf16 = 1 MB
    float* hbuf     = Xi;                          // alias (dead after msg it1)

    // outputs written in place:
    float* out_child  = out;                      // 51200
    float* out_sem    = out + 51200;              // 5700
    float* out_exists = out + 56900;              // 100
    float* out_elog   = out + 57000;              // 40000

    // 1. w3prep + child split-K partials + zero flag/jcount
    front_kernel<<<912, 256, 0, stream>>>(W_ne, W3t, parent, W_parent, scratch, flag);

    // 2. child reduce + relu + exists -> out + node_ok
    child_red_ex<<<50, 256, 0, stream>>>(scratch, b_parent, W_exists, b_exists,
                                         child_bufs, out_exists, node_ok);

    // 3. Xi/Xj/Abuf/Bbuf: quad GEMM, split-K x4, float4 B  (800 blocks)
    spk_g4<0, 512, 4><<<dim3(8, 25, 4), 256, 0, stream>>>(child_bufs,
        W_el, W_el + 512 * 512, W_ne, W_ne + 512 * 512, scratch);
    spk_reduceN<<<800, 256, 0, stream>>>(scratch, 4, 4, Xi, Xj, Abuf, Bbuf,
                                         b_el, nullptr, b_ne, nullptr, 0);

    // 4. edge logits -> out, compaction
    elog_kernel<<<2500, 256, 0, stream>>>(Xi, Xj, W_ee, b_ee, node_ok, out_elog, flag,
                                          jcount, jlist);

    // 5-7. message iterations (parallel j-tiles + reduce)
    for (int it = 0; it < 2; ++it) {
        const float* cprev = child_bufs + it * MH;
        float* cnext = child_bufs + (it + 1) * MH;
        if (it == 1) {
            spk_g4<0, 512, 2><<<dim3(4, 25, 4), 256, 0, stream>>>(cprev,
                W_ne + WNE_IT, W_ne + WNE_IT + 512 * 512, nullptr, nullptr, scratch);
            spk_reduceN<<<400, 256, 0, stream>>>(scratch, 4, 2, Abuf, Bbuf, nullptr, nullptr,
                                                 b_ne + 512, nullptr, nullptr, nullptr, 0);
        }
        msgmfma<<<dim3(7, M_NODES), 512, 0, stream>>>(
            Xi, Xj, Abuf, Bbuf,
            W3t + (size_t)it * 262144,
            W_ne + (size_t)it * WNE_IT + 1536 * 512,
            out_elog, jcount, jlist, scratch);
        msgreduce_kernel<<<200, 256, 0, stream>>>(scratch, cprev, cnext, flag, jcount);
    }

    // 8. h = relu(hcat @ W_child + b_child): split-K x12, float4 B (600 blocks)
    spk_g4<1, 1536, 1><<<dim3(2, 25, 12), 256, 0, stream>>>(child_bufs,
        W_child, nullptr, nullptr, nullptr, scratch);
    spk_reduceN<<<200, 256, 0, stream>>>(scratch, 12, 1, hbuf, nullptr, nullptr, nullptr,
                                         b_child, nullptr, nullptr, nullptr, 1);

    // 9. child_out + sem -> out directly (scalar dual, split-K x4: 900 blocks)
    spk_gemm<0><<<dim3(9, 25, 4), 256, 0, stream>>>(hbuf, 512,
        W_child2, 512, W_sem, 57, scratch);
    spk_reduce<<<223, 256, 0, stream>>>(scratch, 4, b_child2, 1, out_child, 512,
                                        b_sem, 0, out_sem, 57);
}